// Round 12
// baseline (1043.581 us; speedup 1.0000x reference)
//
#include <hip/hip_runtime.h>

// x [T,B,NI] fp32, W [NO,NI] fp32 -> spk_rec [T,B,NO], mem_rec [T,B,NO]
// VERIFIED bit-exact (rounds 9-11): cur = per-element fold of 4 ascending-k
// FMA chains over K-blocks [512x4] (left-assoc fold); scan = fp32
// separate-rounding: reset=(mem>1); mem=((0.9f*mem)+cur)-reset; spk=(mem>1)
#define T_STEPS 100
#define BATCH   128
#define NI      2048
#define NO      1024
#define M_TOT   (T_STEPS * BATCH)        // 12800
#define TOTAL   (T_STEPS * BATCH * NO)   // 13107200 per output tensor
#define BNTOT   (BATCH * NO)             // 131072
#define X_ELEMS (M_TOT * NI)             // 26214400

#define BMf 64
#define BNf 128
#define BKs 16
#define NSLAB (NI / BKs)   // 128
#define LDA (BMf + 4)      // 68
#define LDB (BNf + 4)      // 132

// 256 threads, thread tile 4m x 8n, grid (8, 200) = 1600 blocks.
// Software-pipelined: LDS double-buffer + register prefetch, 1 barrier/slab.
__global__ __launch_bounds__(256) void gemm_512fold(const float* __restrict__ X,
                                                    const float* __restrict__ W,
                                                    float* __restrict__ curOut) {
    __shared__ float As[2][BKs][LDA];   // transposed: As[p][k][m]
    __shared__ float Bs[2][BKs][LDB];   // transposed: Bs[p][k][n]

    const int tid = threadIdx.x;
    const int tx  = tid & 15;        // cols n0 + tx*4 + jj  and  +64
    const int ty  = tid >> 4;        // rows m0 + ty*4 + i
    const int m0  = blockIdx.y * BMf;
    const int n0  = blockIdx.x * BNf;

    const int ar = tid >> 2;         // A staging row 0..63
    const int ak = (tid & 3) * 4;    // A staging k base (one quad)
    const int br = tid >> 1;         // B staging row 0..127
    const int bk = (tid & 1) * 8;    // B staging k base (two quads: bk, bk+4)

    const float* Xp = &X[(size_t)(m0 + ar) * NI + ak];
    const float* Wp = &W[(size_t)(n0 + br) * NI + bk];

    float ch[4][8]  = {};   // current 512-chain accumulators
    float tot[4][8] = {};   // left-assoc inter-chain fold

    // ---- prologue: stage slab 0 into buf 0 ----
    float4 pa  = *reinterpret_cast<const float4*>(&Xp[0]);
    float4 pb0 = *reinterpret_cast<const float4*>(&Wp[0]);
    float4 pb1 = *reinterpret_cast<const float4*>(&Wp[4]);
    As[0][ak + 0][ar] = pa.x;  As[0][ak + 1][ar] = pa.y;
    As[0][ak + 2][ar] = pa.z;  As[0][ak + 3][ar] = pa.w;
    Bs[0][bk + 0][br] = pb0.x; Bs[0][bk + 1][br] = pb0.y;
    Bs[0][bk + 2][br] = pb0.z; Bs[0][bk + 3][br] = pb0.w;
    Bs[0][bk + 4][br] = pb1.x; Bs[0][bk + 5][br] = pb1.y;
    Bs[0][bk + 6][br] = pb1.z; Bs[0][bk + 7][br] = pb1.w;
    __syncthreads();

    #pragma unroll 1
    for (int s = 0; s < NSLAB; ++s) {
        const int p = s & 1;

        // issue next slab's global loads early (latency hides under compute)
        if (s < NSLAB - 1) {
            const int kn = (s + 1) * BKs;
            pa  = *reinterpret_cast<const float4*>(&Xp[kn]);
            pb0 = *reinterpret_cast<const float4*>(&Wp[kn]);
            pb1 = *reinterpret_cast<const float4*>(&Wp[kn + 4]);
        }

        // chain restart boundaries (KC = 512): slabs 32, 64, 96
        if (s == 32 || s == 64 || s == 96) {
            #pragma unroll
            for (int i = 0; i < 4; ++i)
                #pragma unroll
                for (int j = 0; j < 8; ++j) {
                    tot[i][j] = __fadd_rn(tot[i][j], ch[i][j]);
                    ch[i][j]  = 0.0f;
                }
        }

        // ---- compute: ascending k, FMA, one accumulator per element ----
        #pragma unroll
        for (int kk = 0; kk < BKs; ++kk) {
            float a[4], b[8];
            *reinterpret_cast<float4*>(&a[0]) =
                *reinterpret_cast<const float4*>(&As[p][kk][ty * 4]);
            *reinterpret_cast<float4*>(&b[0]) =
                *reinterpret_cast<const float4*>(&Bs[p][kk][tx * 4]);
            *reinterpret_cast<float4*>(&b[4]) =
                *reinterpret_cast<const float4*>(&Bs[p][kk][64 + tx * 4]);
            #pragma unroll
            for (int i = 0; i < 4; ++i)
                #pragma unroll
                for (int j = 0; j < 8; ++j)
                    ch[i][j] = __fmaf_rn(a[i], b[j], ch[i][j]);
        }

        // ---- write prefetched slab to alternate buffer, single barrier ----
        if (s < NSLAB - 1) {
            const int q = p ^ 1;
            As[q][ak + 0][ar] = pa.x;  As[q][ak + 1][ar] = pa.y;
            As[q][ak + 2][ar] = pa.z;  As[q][ak + 3][ar] = pa.w;
            Bs[q][bk + 0][br] = pb0.x; Bs[q][bk + 1][br] = pb0.y;
            Bs[q][bk + 2][br] = pb0.z; Bs[q][bk + 3][br] = pb0.w;
            Bs[q][bk + 4][br] = pb1.x; Bs[q][bk + 5][br] = pb1.y;
            Bs[q][bk + 6][br] = pb1.z; Bs[q][bk + 7][br] = pb1.w;
            __syncthreads();
        }
    }

    // ---- epilogue: final fold, float4 stores ----
    #pragma unroll
    for (int i = 0; i < 4; ++i) {
        const size_t rowbase = (size_t)(m0 + ty * 4 + i) * NO + n0;
        #pragma unroll
        for (int h = 0; h < 2; ++h) {
            float4 v;
            v.x = __fadd_rn(tot[i][h * 4 + 0], ch[i][h * 4 + 0]);
            v.y = __fadd_rn(tot[i][h * 4 + 1], ch[i][h * 4 + 1]);
            v.z = __fadd_rn(tot[i][h * 4 + 2], ch[i][h * 4 + 2]);
            v.w = __fadd_rn(tot[i][h * 4 + 3], ch[i][h * 4 + 3]);
            *reinterpret_cast<float4*>(&curOut[rowbase + h * 64 + tx * 4]) = v;
        }
    }
}

// fp32 LIF scan, numpy op order (verified bit-exact), float4 vectorized.
__global__ __launch_bounds__(256) void lif_scan(float* __restrict__ spk,
                                                float* __restrict__ memf) {
    const int idx = (blockIdx.x * blockDim.x + threadIdx.x) * 4;  // 0..BNTOT-4
    float4 mem = make_float4(0.f, 0.f, 0.f, 0.f);
    for (int t = 0; t < T_STEPS; ++t) {
        const size_t i = (size_t)t * BNTOT + idx;
        const float4 cur = *reinterpret_cast<const float4*>(&memf[i]);
        float4 spkv;
        #define STEP(c)                                                   \
        {                                                                 \
            const float reset = (mem.c > 1.0f) ? 1.0f : 0.0f;             \
            float tmp = __fmul_rn(0.9f, mem.c);                           \
            tmp = __fadd_rn(tmp, cur.c);                                  \
            mem.c = __fsub_rn(tmp, reset);                                \
            spkv.c = (mem.c > 1.0f) ? 1.0f : 0.0f;                        \
        }
        STEP(x) STEP(y) STEP(z) STEP(w)
        #undef STEP
        *reinterpret_cast<float4*>(&spk[i])  = spkv;
        *reinterpret_cast<float4*>(&memf[i]) = mem;
    }
}

extern "C" void kernel_launch(void* const* d_in, const int* in_sizes, int n_in,
                              void* d_out, int out_size, void* d_ws, size_t ws_size,
                              hipStream_t stream) {
    const float* X;
    const float* W;
    if (in_sizes[0] == X_ELEMS) { X = (const float*)d_in[0]; W = (const float*)d_in[1]; }
    else                        { X = (const float*)d_in[1]; W = (const float*)d_in[0]; }

    float* spk  = (float*)d_out;     // [T,B,NO]
    float* memf = spk + TOTAL;       // [T,B,NO]  (cur scratch, then mem_rec)

    dim3 gg(NO / BNf, M_TOT / BMf);  // (8, 200) = 1600 blocks
    gemm_512fold<<<gg, 256, 0, stream>>>(X, W, memf);

    lif_scan<<<BNTOT / 4 / 256, 256, 0, stream>>>(spk, memf);
}

// Round 13
// 715.899 us; speedup vs baseline: 1.4577x; 1.4577x over previous
//
#include <hip/hip_runtime.h>

// x [T,B,NI] fp32, W [NO,NI] fp32 -> spk_rec [T,B,NO], mem_rec [T,B,NO]
// VERIFIED bit-exact (rounds 9-12): cur = per-element fold of 4 ascending-k
// FMA chains over K-blocks [512x4] (left-assoc fold); scan = fp32
// separate-rounding: reset=(mem>1); mem=((0.9f*mem)+cur)-reset; spk=(mem>1)
#define T_STEPS 100
#define BATCH   128
#define NI      2048
#define NO      1024
#define M_TOT   (T_STEPS * BATCH)        // 12800
#define TOTAL   (T_STEPS * BATCH * NO)   // 13107200 per output tensor
#define BNTOT   (BATCH * NO)             // 131072
#define X_ELEMS (M_TOT * NI)             // 26214400

#define BMf 64
#define BNf 128
#define BKf 32
#define LDA (BMf + 4)    // 68
#define LDB (BNf + 4)    // 132
#define NXB (NO / BNf)   // 8   n-blocks
#define NYB (M_TOT/BMf)  // 200 m-blocks
#define YPX (NYB / 8)    // 25  y-panels per XCD

// 256 threads, thread tile 4m x 8n, 1-D grid 1600 with XCD-aware mapping:
// XCD k owns y-panels [k*25,(k+1)*25); same-A-panel blocks stay XCD-local.
__global__ __launch_bounds__(256) void gemm_512fold(const float* __restrict__ X,
                                                    const float* __restrict__ W,
                                                    float* __restrict__ curOut) {
    __shared__ float As[BKf][LDA];   // transposed: As[k][m]
    __shared__ float Bs[BKf][LDB];   // transposed: Bs[k][n]

    // XCD swizzle (bijective over 1600): dispatch round-robins blockIdx.x%8
    // across XCDs; make XCD k process (bx = q&7, by = k*25 + q>>3).
    const int orig = blockIdx.x;
    const int k_x  = orig & 7;       // XCD slot
    const int q    = orig >> 3;      // 0..199 sequence within XCD
    const int m0   = (k_x * YPX + (q >> 3)) * BMf;
    const int n0   = (q & 7) * BNf;

    const int tid = threadIdx.x;
    const int tx  = tid & 15;        // cols n0 + tx*4 + jj  and  +64
    const int ty  = tid >> 4;        // rows m0 + ty*4 + i

    const int ar = tid >> 2;         // A staging row 0..63
    const int ak = (tid & 3) * 4;    // A staging k base (two quads: ak, ak+16)
    const int br = tid >> 1;         // B staging row 0..127
    const int bk = (tid & 1) * 4;    // B staging k base (quads: bk+8q)

    float ch[4][8]  = {};   // current 512-chain accumulators
    float tot[4][8] = {};   // left-assoc inter-chain fold

    #pragma unroll 1
    for (int k0 = 0; k0 < NI; k0 += BKf) {
        if (k0 == 512 || k0 == 1024 || k0 == 1536) {
            #pragma unroll
            for (int i = 0; i < 4; ++i)
                #pragma unroll
                for (int j = 0; j < 8; ++j) {
                    tot[i][j] = __fadd_rn(tot[i][j], ch[i][j]);
                    ch[i][j]  = 0.0f;
                }
        }

        // ---- stage K-slab (transposed) ----
        {
            const float4 fa0 = *reinterpret_cast<const float4*>(
                &X[(size_t)(m0 + ar) * NI + k0 + ak]);
            const float4 fa1 = *reinterpret_cast<const float4*>(
                &X[(size_t)(m0 + ar) * NI + k0 + ak + 16]);
            As[ak + 0][ar] = fa0.x;  As[ak + 1][ar] = fa0.y;
            As[ak + 2][ar] = fa0.z;  As[ak + 3][ar] = fa0.w;
            As[ak + 16][ar] = fa1.x; As[ak + 17][ar] = fa1.y;
            As[ak + 18][ar] = fa1.z; As[ak + 19][ar] = fa1.w;
            #pragma unroll
            for (int qq = 0; qq < 4; ++qq) {
                const int kb = bk + qq * 8;
                const float4 fb = *reinterpret_cast<const float4*>(
                    &W[(size_t)(n0 + br) * NI + k0 + kb]);
                Bs[kb + 0][br] = fb.x; Bs[kb + 1][br] = fb.y;
                Bs[kb + 2][br] = fb.z; Bs[kb + 3][br] = fb.w;
            }
        }
        __syncthreads();

        // ---- compute: ascending k, FMA, one accumulator per element ----
        #pragma unroll
        for (int kk = 0; kk < BKf; ++kk) {
            float a[4], b[8];
            *reinterpret_cast<float4*>(&a[0]) =
                *reinterpret_cast<const float4*>(&As[kk][ty * 4]);
            *reinterpret_cast<float4*>(&b[0]) =
                *reinterpret_cast<const float4*>(&Bs[kk][tx * 4]);
            *reinterpret_cast<float4*>(&b[4]) =
                *reinterpret_cast<const float4*>(&Bs[kk][64 + tx * 4]);
            #pragma unroll
            for (int i = 0; i < 4; ++i)
                #pragma unroll
                for (int j = 0; j < 8; ++j)
                    ch[i][j] = __fmaf_rn(a[i], b[j], ch[i][j]);
        }
        __syncthreads();
    }

    // ---- epilogue: final fold, float4 stores ----
    #pragma unroll
    for (int i = 0; i < 4; ++i) {
        const size_t rowbase = (size_t)(m0 + ty * 4 + i) * NO + n0;
        #pragma unroll
        for (int h = 0; h < 2; ++h) {
            float4 v;
            v.x = __fadd_rn(tot[i][h * 4 + 0], ch[i][h * 4 + 0]);
            v.y = __fadd_rn(tot[i][h * 4 + 1], ch[i][h * 4 + 1]);
            v.z = __fadd_rn(tot[i][h * 4 + 2], ch[i][h * 4 + 2]);
            v.w = __fadd_rn(tot[i][h * 4 + 3], ch[i][h * 4 + 3]);
            *reinterpret_cast<float4*>(&curOut[rowbase + h * 64 + tx * 4]) = v;
        }
    }
}

// fp32 LIF scan, numpy op order (verified bit-exact), float4 vectorized.
__global__ __launch_bounds__(256) void lif_scan(float* __restrict__ spk,
                                                float* __restrict__ memf) {
    const int idx = (blockIdx.x * blockDim.x + threadIdx.x) * 4;  // 0..BNTOT-4
    float4 mem = make_float4(0.f, 0.f, 0.f, 0.f);
    for (int t = 0; t < T_STEPS; ++t) {
        const size_t i = (size_t)t * BNTOT + idx;
        const float4 cur = *reinterpret_cast<const float4*>(&memf[i]);
        float4 spkv;
        #define STEP(c)                                                   \
        {                                                                 \
            const float reset = (mem.c > 1.0f) ? 1.0f : 0.0f;             \
            float tmp = __fmul_rn(0.9f, mem.c);                           \
            tmp = __fadd_rn(tmp, cur.c);                                  \
            mem.c = __fsub_rn(tmp, reset);                                \
            spkv.c = (mem.c > 1.0f) ? 1.0f : 0.0f;                        \
        }
        STEP(x) STEP(y) STEP(z) STEP(w)
        #undef STEP
        *reinterpret_cast<float4*>(&spk[i])  = spkv;
        *reinterpret_cast<float4*>(&memf[i]) = mem;
    }
}

extern "C" void kernel_launch(void* const* d_in, const int* in_sizes, int n_in,
                              void* d_out, int out_size, void* d_ws, size_t ws_size,
                              hipStream_t stream) {
    const float* X;
    const float* W;
    if (in_sizes[0] == X_ELEMS) { X = (const float*)d_in[0]; W = (const float*)d_in[1]; }
    else                        { X = (const float*)d_in[1]; W = (const float*)d_in[0]; }

    float* spk  = (float*)d_out;     // [T,B,NO]
    float* memf = spk + TOTAL;       // [T,B,NO]  (cur scratch, then mem_rec)

    gemm_512fold<<<NXB * NYB, 256, 0, stream>>>(X, W, memf);   // 1600 blocks, swizzled

    lif_scan<<<BNTOT / 4 / 256, 256, 0, stream>>>(spk, memf);
}

// Round 14
// 653.490 us; speedup vs baseline: 1.5969x; 1.0955x over previous
//
#include <hip/hip_runtime.h>

// x [T,B,NI] fp32, W [NO,NI] fp32 -> spk_rec [T,B,NO], mem_rec [T,B,NO]
// VERIFIED bit-exact (rounds 9-13): cur = per-element fold of 4 ascending-k
// FMA chains over K-blocks [512x4], combined left-assoc ((c0+c1)+c2)+c3;
// scan = fp32 separate-rounding: reset=(mem>1); mem=((0.9f*mem)+cur)-reset.
// This round: 4-way K-split along the fold boundaries (each block computes
// ONE 512-chain), fused fold+scan kernel. Bit-exact by construction.
#define T_STEPS 100
#define BATCH   128
#define NI      2048
#define NO      1024
#define M_TOT   (T_STEPS * BATCH)        // 12800
#define TOTAL   (T_STEPS * BATCH * NO)   // 13107200 per output tensor
#define BNTOT   (BATCH * NO)             // 131072
#define X_ELEMS (M_TOT * NI)             // 26214400

#define BMf 64
#define BNf 128
#define BKf 32
#define LDA (BMf + 4)    // 68
#define LDB (BNf + 4)    // 132
#define NXB (NO / BNf)   // 8    n-blocks
#define NYB (M_TOT/BMf)  // 200  m-blocks
#define YPX (NYB / 8)    // 25   m-panels per XCD

// ---- K-split GEMM: one KC=512 chain per block. Grid 6400 (1-D, swizzled):
// xcd = orig&7; q = orig>>3; n = q&7; t = q>>3; chain = t/25; my = t%25.
__global__ __launch_bounds__(256) void gemm_chain512(const float* __restrict__ X,
                                                     const float* __restrict__ W,
                                                     float* __restrict__ p0,
                                                     float* __restrict__ p1,
                                                     float* __restrict__ p2,
                                                     float* __restrict__ p3) {
    __shared__ float As[BKf][LDA];   // transposed: As[k][m]
    __shared__ float Bs[BKf][LDB];   // transposed: Bs[k][n]

    const int orig  = blockIdx.x;
    const int xcd   = orig & 7;
    const int q     = orig >> 3;       // 0..799
    const int n0    = (q & 7) * BNf;
    const int t     = q >> 3;          // 0..99
    const int chain = t / 25;          // 0..3
    const int my    = t - chain * 25;  // 0..24
    const int m0    = (xcd * YPX + my) * BMf;
    const int kbase = chain * 512;
    float* out = (chain == 0) ? p0 : (chain == 1) ? p1 : (chain == 2) ? p2 : p3;

    const int tid = threadIdx.x;
    const int tx  = tid & 15;        // cols n0 + tx*4 + jj  and  +64
    const int ty  = tid >> 4;        // rows m0 + ty*4 + i

    const int ar = tid >> 2;         // A staging row 0..63
    const int ak = (tid & 3) * 4;    // A staging k base (two quads: ak, ak+16)
    const int br = tid >> 1;         // B staging row 0..127
    const int bk = (tid & 1) * 4;    // B staging k base (quads: bk+8q)

    float ch[4][8] = {};   // the 512-chain accumulators (ascending k, FMA)

    #pragma unroll 1
    for (int k0 = kbase; k0 < kbase + 512; k0 += BKf) {
        // ---- stage K-slab (transposed) ----
        {
            const float4 fa0 = *reinterpret_cast<const float4*>(
                &X[(size_t)(m0 + ar) * NI + k0 + ak]);
            const float4 fa1 = *reinterpret_cast<const float4*>(
                &X[(size_t)(m0 + ar) * NI + k0 + ak + 16]);
            As[ak + 0][ar] = fa0.x;  As[ak + 1][ar] = fa0.y;
            As[ak + 2][ar] = fa0.z;  As[ak + 3][ar] = fa0.w;
            As[ak + 16][ar] = fa1.x; As[ak + 17][ar] = fa1.y;
            As[ak + 18][ar] = fa1.z; As[ak + 19][ar] = fa1.w;
            #pragma unroll
            for (int qq = 0; qq < 4; ++qq) {
                const int kb = bk + qq * 8;
                const float4 fb = *reinterpret_cast<const float4*>(
                    &W[(size_t)(n0 + br) * NI + k0 + kb]);
                Bs[kb + 0][br] = fb.x; Bs[kb + 1][br] = fb.y;
                Bs[kb + 2][br] = fb.z; Bs[kb + 3][br] = fb.w;
            }
        }
        __syncthreads();

        // ---- compute: ascending k, FMA, one accumulator per element ----
        #pragma unroll
        for (int kk = 0; kk < BKf; ++kk) {
            float a[4], b[8];
            *reinterpret_cast<float4*>(&a[0]) =
                *reinterpret_cast<const float4*>(&As[kk][ty * 4]);
            *reinterpret_cast<float4*>(&b[0]) =
                *reinterpret_cast<const float4*>(&Bs[kk][tx * 4]);
            *reinterpret_cast<float4*>(&b[4]) =
                *reinterpret_cast<const float4*>(&Bs[kk][64 + tx * 4]);
            #pragma unroll
            for (int i = 0; i < 4; ++i)
                #pragma unroll
                for (int j = 0; j < 8; ++j)
                    ch[i][j] = __fmaf_rn(a[i], b[j], ch[i][j]);
        }
        __syncthreads();
    }

    // ---- epilogue: store chain partial, float4 stores ----
    #pragma unroll
    for (int i = 0; i < 4; ++i) {
        const size_t rowbase = (size_t)(m0 + ty * 4 + i) * NO + n0;
        #pragma unroll
        for (int h = 0; h < 2; ++h) {
            float4 v;
            v.x = ch[i][h * 4 + 0]; v.y = ch[i][h * 4 + 1];
            v.z = ch[i][h * 4 + 2]; v.w = ch[i][h * 4 + 3];
            *reinterpret_cast<float4*>(&out[rowbase + h * 64 + tx * 4]) = v;
        }
    }
}

// ---- fused fold + LIF scan: cur = ((p0+p1)+p2)+p3 (exact ref order), then
// scan. p0 lives in the spk slot, p1 in the mem slot (same-thread RAW only).
__global__ __launch_bounds__(256) void fold_scan(float* __restrict__ spk,
                                                 float* __restrict__ memf,
                                                 const float* __restrict__ p2,
                                                 const float* __restrict__ p3) {
    const int idx = (blockIdx.x * blockDim.x + threadIdx.x) * 4;
    float4 mem = make_float4(0.f, 0.f, 0.f, 0.f);
    for (int t = 0; t < T_STEPS; ++t) {
        const size_t i = (size_t)t * BNTOT + idx;
        const float4 c0 = *reinterpret_cast<const float4*>(&spk[i]);
        const float4 c1 = *reinterpret_cast<const float4*>(&memf[i]);
        const float4 c2 = *reinterpret_cast<const float4*>(&p2[i]);
        const float4 c3 = *reinterpret_cast<const float4*>(&p3[i]);
        float4 spkv;
        #define STEP(c)                                                     \
        {                                                                   \
            const float cur = __fadd_rn(__fadd_rn(__fadd_rn(c0.c, c1.c),    \
                                                  c2.c), c3.c);             \
            const float reset = (mem.c > 1.0f) ? 1.0f : 0.0f;               \
            float tmp = __fmul_rn(0.9f, mem.c);                             \
            tmp = __fadd_rn(tmp, cur);                                      \
            mem.c = __fsub_rn(tmp, reset);                                  \
            spkv.c = (mem.c > 1.0f) ? 1.0f : 0.0f;                          \
        }
        STEP(x) STEP(y) STEP(z) STEP(w)
        #undef STEP
        *reinterpret_cast<float4*>(&spk[i])  = spkv;
        *reinterpret_cast<float4*>(&memf[i]) = mem;
    }
}

// ================= fallback path (round-13, proven 716 us) =================
__global__ __launch_bounds__(256) void gemm_512fold(const float* __restrict__ X,
                                                    const float* __restrict__ W,
                                                    float* __restrict__ curOut) {
    __shared__ float As[BKf][LDA];
    __shared__ float Bs[BKf][LDB];
    const int orig = blockIdx.x;
    const int k_x  = orig & 7;
    const int q    = orig >> 3;
    const int m0   = (k_x * YPX + (q >> 3)) * BMf;
    const int n0   = (q & 7) * BNf;
    const int tid = threadIdx.x;
    const int tx  = tid & 15;
    const int ty  = tid >> 4;
    const int ar = tid >> 2;
    const int ak = (tid & 3) * 4;
    const int br = tid >> 1;
    const int bk = (tid & 1) * 4;
    float ch[4][8]  = {};
    float tot[4][8] = {};
    #pragma unroll 1
    for (int k0 = 0; k0 < NI; k0 += BKf) {
        if (k0 == 512 || k0 == 1024 || k0 == 1536) {
            #pragma unroll
            for (int i = 0; i < 4; ++i)
                #pragma unroll
                for (int j = 0; j < 8; ++j) {
                    tot[i][j] = __fadd_rn(tot[i][j], ch[i][j]);
                    ch[i][j]  = 0.0f;
                }
        }
        {
            const float4 fa0 = *reinterpret_cast<const float4*>(
                &X[(size_t)(m0 + ar) * NI + k0 + ak]);
            const float4 fa1 = *reinterpret_cast<const float4*>(
                &X[(size_t)(m0 + ar) * NI + k0 + ak + 16]);
            As[ak + 0][ar] = fa0.x;  As[ak + 1][ar] = fa0.y;
            As[ak + 2][ar] = fa0.z;  As[ak + 3][ar] = fa0.w;
            As[ak + 16][ar] = fa1.x; As[ak + 17][ar] = fa1.y;
            As[ak + 18][ar] = fa1.z; As[ak + 19][ar] = fa1.w;
            #pragma unroll
            for (int qq = 0; qq < 4; ++qq) {
                const int kb = bk + qq * 8;
                const float4 fb = *reinterpret_cast<const float4*>(
                    &W[(size_t)(n0 + br) * NI + k0 + kb]);
                Bs[kb + 0][br] = fb.x; Bs[kb + 1][br] = fb.y;
                Bs[kb + 2][br] = fb.z; Bs[kb + 3][br] = fb.w;
            }
        }
        __syncthreads();
        #pragma unroll
        for (int kk = 0; kk < BKf; ++kk) {
            float a[4], b[8];
            *reinterpret_cast<float4*>(&a[0]) =
                *reinterpret_cast<const float4*>(&As[kk][ty * 4]);
            *reinterpret_cast<float4*>(&b[0]) =
                *reinterpret_cast<const float4*>(&Bs[kk][tx * 4]);
            *reinterpret_cast<float4*>(&b[4]) =
                *reinterpret_cast<const float4*>(&Bs[kk][64 + tx * 4]);
            #pragma unroll
            for (int i = 0; i < 4; ++i)
                #pragma unroll
                for (int j = 0; j < 8; ++j)
                    ch[i][j] = __fmaf_rn(a[i], b[j], ch[i][j]);
        }
        __syncthreads();
    }
    #pragma unroll
    for (int i = 0; i < 4; ++i) {
        const size_t rowbase = (size_t)(m0 + ty * 4 + i) * NO + n0;
        #pragma unroll
        for (int h = 0; h < 2; ++h) {
            float4 v;
            v.x = __fadd_rn(tot[i][h * 4 + 0], ch[i][h * 4 + 0]);
            v.y = __fadd_rn(tot[i][h * 4 + 1], ch[i][h * 4 + 1]);
            v.z = __fadd_rn(tot[i][h * 4 + 2], ch[i][h * 4 + 2]);
            v.w = __fadd_rn(tot[i][h * 4 + 3], ch[i][h * 4 + 3]);
            *reinterpret_cast<float4*>(&curOut[rowbase + h * 64 + tx * 4]) = v;
        }
    }
}

__global__ __launch_bounds__(256) void lif_scan(float* __restrict__ spk,
                                                float* __restrict__ memf) {
    const int idx = (blockIdx.x * blockDim.x + threadIdx.x) * 4;
    float4 mem = make_float4(0.f, 0.f, 0.f, 0.f);
    for (int t = 0; t < T_STEPS; ++t) {
        const size_t i = (size_t)t * BNTOT + idx;
        const float4 cur = *reinterpret_cast<const float4*>(&memf[i]);
        float4 spkv;
        #define STEP(c)                                                   \
        {                                                                 \
            const float reset = (mem.c > 1.0f) ? 1.0f : 0.0f;             \
            float tmp = __fmul_rn(0.9f, mem.c);                           \
            tmp = __fadd_rn(tmp, cur.c);                                  \
            mem.c = __fsub_rn(tmp, reset);                                \
            spkv.c = (mem.c > 1.0f) ? 1.0f : 0.0f;                        \
        }
        STEP(x) STEP(y) STEP(z) STEP(w)
        #undef STEP
        *reinterpret_cast<float4*>(&spk[i])  = spkv;
        *reinterpret_cast<float4*>(&memf[i]) = mem;
    }
}

extern "C" void kernel_launch(void* const* d_in, const int* in_sizes, int n_in,
                              void* d_out, int out_size, void* d_ws, size_t ws_size,
                              hipStream_t stream) {
    const float* X;
    const float* W;
    if (in_sizes[0] == X_ELEMS) { X = (const float*)d_in[0]; W = (const float*)d_in[1]; }
    else                        { X = (const float*)d_in[1]; W = (const float*)d_in[0]; }

    float* spk  = (float*)d_out;     // [T,B,NO]
    float* memf = spk + TOTAL;       // [T,B,NO]

    if (ws_size >= (size_t)2 * TOTAL * sizeof(float)) {
        // K-split path: chains c0->spk slot, c1->mem slot, c2/c3 -> workspace
        float* p2 = (float*)d_ws;
        float* p3 = p2 + TOTAL;
        gemm_chain512<<<4 * NXB * NYB, 256, 0, stream>>>(X, W, spk, memf, p2, p3);
        fold_scan<<<BNTOT / 4 / 256, 256, 0, stream>>>(spk, memf, p2, p3);
    } else {
        // fallback: proven round-13 path
        gemm_512fold<<<NXB * NYB, 256, 0, stream>>>(X, W, memf);
        lif_scan<<<BNTOT / 4 / 256, 256, 0, stream>>>(spk, memf);
    }
}

// Round 15
// 635.511 us; speedup vs baseline: 1.6421x; 1.0283x over previous
//
#include <hip/hip_runtime.h>

// x [T,B,NI] fp32, W [NO,NI] fp32 -> spk_rec [T,B,NO], mem_rec [T,B,NO]
// VERIFIED bit-exact (rounds 9-14): cur = per-element fold of 4 ascending-k
// FMA chains over K-blocks [512x4], combined left-assoc ((c0+c1)+c2)+c3;
// scan = fp32 separate-rounding: reset=(mem>1); mem=((0.9f*mem)+cur)-reset.
// Round 15: K-split GEMM upgraded to 128x128 tile, 8x8/thread (halves
// ds_read and barrier cost per FMA). Arithmetic order unchanged.
#define T_STEPS 100
#define BATCH   128
#define NI      2048
#define NO      1024
#define M_TOT   (T_STEPS * BATCH)        // 12800
#define TOTAL   (T_STEPS * BATCH * NO)   // 13107200 per output tensor
#define BNTOT   (BATCH * NO)             // 131072
#define X_ELEMS (M_TOT * NI)             // 26214400

#define BMf 128
#define BNf 128
#define BKf 32
#define LDT 132          // padded LDS row stride (floats)
#define NXB (NO / BNf)   // 8    n-blocks
#define NYB (M_TOT/BMf)  // 100  m-blocks
// grid = NXB * NYB * 4 chains = 3200; per XCD 400 = 8n x 50 (chain,m) pairs

__global__ __launch_bounds__(256, 2) void gemm_chain512(const float* __restrict__ X,
                                                        const float* __restrict__ W,
                                                        float* __restrict__ p0,
                                                        float* __restrict__ p1,
                                                        float* __restrict__ p2,
                                                        float* __restrict__ p3) {
    __shared__ float As[BKf][LDT];   // transposed: As[k][m]
    __shared__ float Bs[BKf][LDT];   // transposed: Bs[k][n]

    // XCD-aware decomposition: xcd owns 50 (chain,m) pairs, n fastest.
    const int orig  = blockIdx.x;
    const int xcd   = orig & 7;
    const int q     = orig >> 3;        // 0..399
    const int n0    = (q & 7) * BNf;
    const int s     = q >> 3;           // 0..49
    const int p     = xcd * 50 + s;     // 0..399
    const int chain = p / 100;          // 0..3
    const int m0    = (p - chain * 100) * BMf;
    const int kbase = chain * 512;
    float* out = (chain == 0) ? p0 : (chain == 1) ? p1 : (chain == 2) ? p2 : p3;

    const int tid = threadIdx.x;
    const int tx  = tid & 15;        // cols n0 + tx*4 + j  and  +64
    const int ty  = tid >> 4;        // rows m0 + ty*4 + i  and  +64

    const int sr = tid >> 1;         // staging row 0..127 (A and B)
    const int sk = (tid & 1) * 16;   // staging k base: 4 quads sk..sk+12

    float ch[8][8] = {};   // the 512-chain accumulators (ascending k, FMA)

    #pragma unroll 1
    for (int k0 = kbase; k0 < kbase + 512; k0 += BKf) {
        // ---- stage K-slab (transposed): 4 float4 each from X and W ----
        #pragma unroll
        for (int qq = 0; qq < 4; ++qq) {
            const int kb = sk + qq * 4;
            const float4 fa = *reinterpret_cast<const float4*>(
                &X[(size_t)(m0 + sr) * NI + k0 + kb]);
            As[kb + 0][sr] = fa.x; As[kb + 1][sr] = fa.y;
            As[kb + 2][sr] = fa.z; As[kb + 3][sr] = fa.w;
            const float4 fb = *reinterpret_cast<const float4*>(
                &W[(size_t)(n0 + sr) * NI + k0 + kb]);
            Bs[kb + 0][sr] = fb.x; Bs[kb + 1][sr] = fb.y;
            Bs[kb + 2][sr] = fb.z; Bs[kb + 3][sr] = fb.w;
        }
        __syncthreads();

        // ---- compute: ascending k, FMA, one accumulator per element ----
        #pragma unroll
        for (int kk = 0; kk < BKf; ++kk) {
            float a[8], b[8];
            *reinterpret_cast<float4*>(&a[0]) =
                *reinterpret_cast<const float4*>(&As[kk][ty * 4]);
            *reinterpret_cast<float4*>(&a[4]) =
                *reinterpret_cast<const float4*>(&As[kk][64 + ty * 4]);
            *reinterpret_cast<float4*>(&b[0]) =
                *reinterpret_cast<const float4*>(&Bs[kk][tx * 4]);
            *reinterpret_cast<float4*>(&b[4]) =
                *reinterpret_cast<const float4*>(&Bs[kk][64 + tx * 4]);
            #pragma unroll
            for (int i = 0; i < 8; ++i)
                #pragma unroll
                for (int j = 0; j < 8; ++j)
                    ch[i][j] = __fmaf_rn(a[i], b[j], ch[i][j]);
        }
        __syncthreads();
    }

    // ---- epilogue: store chain partial (quadrant layout), float4 stores ----
    #pragma unroll
    for (int i = 0; i < 8; ++i) {
        const int row = m0 + ((i < 4) ? (ty * 4 + i) : (64 + ty * 4 + i - 4));
        const size_t rowbase = (size_t)row * NO + n0;
        #pragma unroll
        for (int h = 0; h < 2; ++h) {
            float4 v;
            v.x = ch[i][h * 4 + 0]; v.y = ch[i][h * 4 + 1];
            v.z = ch[i][h * 4 + 2]; v.w = ch[i][h * 4 + 3];
            *reinterpret_cast<float4*>(&out[rowbase + h * 64 + tx * 4]) = v;
        }
    }
}

// ---- fused fold + LIF scan: cur = ((p0+p1)+p2)+p3 (exact ref order), then
// scan. p0 lives in the spk slot, p1 in the mem slot (same-thread RAW only).
__global__ __launch_bounds__(256) void fold_scan(float* __restrict__ spk,
                                                 float* __restrict__ memf,
                                                 const float* __restrict__ p2,
                                                 const float* __restrict__ p3) {
    const int idx = (blockIdx.x * blockDim.x + threadIdx.x) * 4;
    float4 mem = make_float4(0.f, 0.f, 0.f, 0.f);
    for (int t = 0; t < T_STEPS; ++t) {
        const size_t i = (size_t)t * BNTOT + idx;
        const float4 c0 = *reinterpret_cast<const float4*>(&spk[i]);
        const float4 c1 = *reinterpret_cast<const float4*>(&memf[i]);
        const float4 c2 = *reinterpret_cast<const float4*>(&p2[i]);
        const float4 c3 = *reinterpret_cast<const float4*>(&p3[i]);
        float4 spkv;
        #define STEP(c)                                                     \
        {                                                                   \
            const float cur = __fadd_rn(__fadd_rn(__fadd_rn(c0.c, c1.c),    \
                                                  c2.c), c3.c);             \
            const float reset = (mem.c > 1.0f) ? 1.0f : 0.0f;               \
            float tmp = __fmul_rn(0.9f, mem.c);                             \
            tmp = __fadd_rn(tmp, cur);                                      \
            mem.c = __fsub_rn(tmp, reset);                                  \
            spkv.c = (mem.c > 1.0f) ? 1.0f : 0.0f;                          \
        }
        STEP(x) STEP(y) STEP(z) STEP(w)
        #undef STEP
        *reinterpret_cast<float4*>(&spk[i])  = spkv;
        *reinterpret_cast<float4*>(&memf[i]) = mem;
    }
}

// ============== fallback path (round-13 single-kernel, proven) ==============
#define BMs 64
#define LDAs (BMs + 4)
#define NYBs (M_TOT / BMs)   // 200
#define YPXs (NYBs / 8)      // 25

__global__ __launch_bounds__(256) void gemm_512fold(const float* __restrict__ X,
                                                    const float* __restrict__ W,
                                                    float* __restrict__ curOut) {
    __shared__ float As[BKf][LDAs];
    __shared__ float Bs[BKf][LDT];
    const int orig = blockIdx.x;
    const int k_x  = orig & 7;
    const int q    = orig >> 3;
    const int m0   = (k_x * YPXs + (q >> 3)) * BMs;
    const int n0   = (q & 7) * BNf;
    const int tid = threadIdx.x;
    const int tx  = tid & 15;
    const int ty  = tid >> 4;
    const int ar = tid >> 2;
    const int ak = (tid & 3) * 4;
    const int br = tid >> 1;
    const int bk = (tid & 1) * 4;
    float ch[4][8]  = {};
    float tot[4][8] = {};
    #pragma unroll 1
    for (int k0 = 0; k0 < NI; k0 += BKf) {
        if (k0 == 512 || k0 == 1024 || k0 == 1536) {
            #pragma unroll
            for (int i = 0; i < 4; ++i)
                #pragma unroll
                for (int j = 0; j < 8; ++j) {
                    tot[i][j] = __fadd_rn(tot[i][j], ch[i][j]);
                    ch[i][j]  = 0.0f;
                }
        }
        {
            const float4 fa0 = *reinterpret_cast<const float4*>(
                &X[(size_t)(m0 + ar) * NI + k0 + ak]);
            const float4 fa1 = *reinterpret_cast<const float4*>(
                &X[(size_t)(m0 + ar) * NI + k0 + ak + 16]);
            As[ak + 0][ar] = fa0.x;  As[ak + 1][ar] = fa0.y;
            As[ak + 2][ar] = fa0.z;  As[ak + 3][ar] = fa0.w;
            As[ak + 16][ar] = fa1.x; As[ak + 17][ar] = fa1.y;
            As[ak + 18][ar] = fa1.z; As[ak + 19][ar] = fa1.w;
            #pragma unroll
            for (int qq = 0; qq < 4; ++qq) {
                const int kb = bk + qq * 8;
                const float4 fb = *reinterpret_cast<const float4*>(
                    &W[(size_t)(n0 + br) * NI + k0 + kb]);
                Bs[kb + 0][br] = fb.x; Bs[kb + 1][br] = fb.y;
                Bs[kb + 2][br] = fb.z; Bs[kb + 3][br] = fb.w;
            }
        }
        __syncthreads();
        #pragma unroll
        for (int kk = 0; kk < BKf; ++kk) {
            float a[4], b[8];
            *reinterpret_cast<float4*>(&a[0]) =
                *reinterpret_cast<const float4*>(&As[kk][ty * 4]);
            *reinterpret_cast<float4*>(&b[0]) =
                *reinterpret_cast<const float4*>(&Bs[kk][tx * 4]);
            *reinterpret_cast<float4*>(&b[4]) =
                *reinterpret_cast<const float4*>(&Bs[kk][64 + tx * 4]);
            #pragma unroll
            for (int i = 0; i < 4; ++i)
                #pragma unroll
                for (int j = 0; j < 8; ++j)
                    ch[i][j] = __fmaf_rn(a[i], b[j], ch[i][j]);
        }
        __syncthreads();
    }
    #pragma unroll
    for (int i = 0; i < 4; ++i) {
        const size_t rowbase = (size_t)(m0 + ty * 4 + i) * NO + n0;
        #pragma unroll
        for (int h = 0; h < 2; ++h) {
            float4 v;
            v.x = __fadd_rn(tot[i][h * 4 + 0], ch[i][h * 4 + 0]);
            v.y = __fadd_rn(tot[i][h * 4 + 1], ch[i][h * 4 + 1]);
            v.z = __fadd_rn(tot[i][h * 4 + 2], ch[i][h * 4 + 2]);
            v.w = __fadd_rn(tot[i][h * 4 + 3], ch[i][h * 4 + 3]);
            *reinterpret_cast<float4*>(&curOut[rowbase + h * 64 + tx * 4]) = v;
        }
    }
}

__global__ __launch_bounds__(256) void lif_scan(float* __restrict__ spk,
                                                float* __restrict__ memf) {
    const int idx = (blockIdx.x * blockDim.x + threadIdx.x) * 4;
    float4 mem = make_float4(0.f, 0.f, 0.f, 0.f);
    for (int t = 0; t < T_STEPS; ++t) {
        const size_t i = (size_t)t * BNTOT + idx;
        const float4 cur = *reinterpret_cast<const float4*>(&memf[i]);
        float4 spkv;
        #define STEP(c)                                                   \
        {                                                                 \
            const float reset = (mem.c > 1.0f) ? 1.0f : 0.0f;             \
            float tmp = __fmul_rn(0.9f, mem.c);                           \
            tmp = __fadd_rn(tmp, cur.c);                                  \
            mem.c = __fsub_rn(tmp, reset);                                \
            spkv.c = (mem.c > 1.0f) ? 1.0f : 0.0f;                        \
        }
        STEP(x) STEP(y) STEP(z) STEP(w)
        #undef STEP
        *reinterpret_cast<float4*>(&spk[i])  = spkv;
        *reinterpret_cast<float4*>(&memf[i]) = mem;
    }
}

extern "C" void kernel_launch(void* const* d_in, const int* in_sizes, int n_in,
                              void* d_out, int out_size, void* d_ws, size_t ws_size,
                              hipStream_t stream) {
    const float* X;
    const float* W;
    if (in_sizes[0] == X_ELEMS) { X = (const float*)d_in[0]; W = (const float*)d_in[1]; }
    else                        { X = (const float*)d_in[1]; W = (const float*)d_in[0]; }

    float* spk  = (float*)d_out;     // [T,B,NO]
    float* memf = spk + TOTAL;       // [T,B,NO]

    if (ws_size >= (size_t)2 * TOTAL * sizeof(float)) {
        // K-split path: chains c0->spk slot, c1->mem slot, c2/c3 -> workspace
        float* p2 = (float*)d_ws;
        float* p3 = p2 + TOTAL;
        gemm_chain512<<<4 * NXB * NYB, 256, 0, stream>>>(X, W, spk, memf, p2, p3);
        fold_scan<<<BNTOT / 4 / 256, 256, 0, stream>>>(spk, memf, p2, p3);
    } else {
        // fallback: proven round-13 path
        gemm_512fold<<<NXB * NYBs, 256, 0, stream>>>(X, W, memf);
        lif_scan<<<BNTOT / 4 / 256, 256, 0, stream>>>(spk, memf);
    }
}